// Round 22
// baseline (142.257 us; speedup 1.0000x reference)
//
#include <hip/hip_runtime.h>
#include <hip/hip_bf16.h>
#include <math.h>

#define NB 32768
#define ND 768
#define NC 474
#define NCP 512
#define NE 3
#define NH 128
#define GAP_THR 0.035f
#define XB_OFF 4194304ull

typedef short v8s __attribute__((ext_vector_type(8)));
typedef float v4f __attribute__((ext_vector_type(4)));
typedef unsigned long long u64;

#define GLD16(gp, lp) __builtin_amdgcn_global_load_lds( \
    (const __attribute__((address_space(1))) void*)(gp), \
    (__attribute__((address_space(3))) void*)(lp), 16, 0, 0)

static __device__ __forceinline__ short f2bf(float f) {
    __hip_bfloat16 h = __float2bfloat16(f);
    return *reinterpret_cast<short*>(&h);
}

static __device__ __forceinline__ void vmwait(int n) {
    switch (n) {
    case 0:  asm volatile("s_waitcnt vmcnt(0)"  ::: "memory"); break;
    case 5:  asm volatile("s_waitcnt vmcnt(5)"  ::: "memory"); break;
    case 6:  asm volatile("s_waitcnt vmcnt(6)"  ::: "memory"); break;
    case 12: asm volatile("s_waitcnt vmcnt(12)" ::: "memory"); break;
    default: asm volatile("s_waitcnt vmcnt(10)" ::: "memory"); break;
    }
}

// ---------------------------------------------------------------------------
// pre_kernel: fused prep (blocks 0..623) + ln_convert (blocks 624..2671).
// prep: hwbT[e][c][k] = bf16(gamma*hw) transposed + slot-swizzled; w1bT from
//   w1; per-32k-chunk bias partials bpG = sum_k gamma*hw, bpB = sum_k beta*hw
//   (non-atomic overwrite -> no init needed).
// ln: xb = bf16(x); murs = (mu, rsqrt(var+eps)); first ln block zeroes counts.
// ---------------------------------------------------------------------------
__global__ __launch_bounds__(256) void pre_kernel(
    const float* __restrict__ hw, const float* __restrict__ gamma,
    const float* __restrict__ beta, const float* __restrict__ w1,
    const float* __restrict__ x,
    short* __restrict__ hwbT, short* __restrict__ w1bT,
    float* __restrict__ bpB, float* __restrict__ bpG,
    float2* __restrict__ murs, short* __restrict__ xb,
    u64* __restrict__ counts)
{
    const int t = threadIdx.x;
    if (blockIdx.x >= 624) {
        // -------- ln_convert branch --------
        if (blockIdx.x == 624 && t == 0) *counts = 0ull;
        const int row = (blockIdx.x - 624) * 16 + (t >> 4);
        const int q = t & 15;
        const float* xr = x + (size_t)row * ND;
        short* xo = xb + (size_t)row * ND;
        float4 v[12];
        #pragma unroll
        for (int i = 0; i < 12; ++i)
            v[i] = *(const float4*)(xr + (i * 16 + q) * 4);
        float s1 = 0.f, s2 = 0.f;
        #pragma unroll
        for (int i = 0; i < 12; ++i) {
            s1 += v[i].x + v[i].y + v[i].z + v[i].w;
            s2 += v[i].x*v[i].x + v[i].y*v[i].y + v[i].z*v[i].z + v[i].w*v[i].w;
        }
        #pragma unroll
        for (int i = 0; i < 12; ++i) {
            short4 o;
            o.x = f2bf(v[i].x); o.y = f2bf(v[i].y);
            o.z = f2bf(v[i].z); o.w = f2bf(v[i].w);
            *(short4*)(xo + (i * 16 + q) * 4) = o;
        }
        s1 += __shfl_xor(s1, 1); s2 += __shfl_xor(s2, 1);
        s1 += __shfl_xor(s1, 2); s2 += __shfl_xor(s2, 2);
        s1 += __shfl_xor(s1, 4); s2 += __shfl_xor(s2, 4);
        s1 += __shfl_xor(s1, 8); s2 += __shfl_xor(s2, 8);
        if (q == 0) {
            const float mu = s1 * (1.f / 768.f);
            const float var = s2 * (1.f / 768.f) - mu * mu;
            murs[row] = make_float2(mu, rsqrtf(var + 1e-5f));
        }
        return;
    }
    // -------- prep branch --------
    __shared__ float T[32][72];
    __shared__ float U[32][72];
    const int id = blockIdx.x;
    const float* src; short* dst; int stride, ncs; int e = 0, cc, kc;
    bool is_exp = (id < 576);
    if (is_exp) {
        e = id / 192; const int r2 = id % 192; cc = r2 / 24; kc = r2 % 24;
        src = hw + (size_t)e * ND * NC; stride = NC; ncs = NC;
        dst = hwbT + (size_t)e * NCP * ND;
    } else {
        const int j = id - 576; cc = j / 24; kc = j % 24;
        src = w1; stride = NH; ncs = NH; dst = w1bT;
    }
    const int c0 = cc * 64, k0 = kc * 32;
    {
        const int kl = t >> 3, c8 = (t & 7) * 8;
        const float g  = is_exp ? gamma[e * ND + k0 + kl] : 1.f;
        const float bb = is_exp ? beta[e * ND + k0 + kl]  : 0.f;
        #pragma unroll
        for (int j = 0; j < 8; ++j) {
            const int cg = c0 + c8 + j;
            const float v = (cg < ncs) ? src[(size_t)(k0 + kl) * stride + cg] : 0.f;
            T[kl][c8 + j] = v * g;
            U[kl][c8 + j] = v * bb;
        }
    }
    __syncthreads();
    {
        const int cl = t >> 2, q = t & 3;
        const int cg = c0 + cl;
        const int sp = q ^ ((cg >> 1) & 3);
        union { short s[8]; int4 v; } u;
        #pragma unroll
        for (int j = 0; j < 8; ++j) u.s[j] = f2bf(T[q * 8 + j][cl]);
        *(int4*)(dst + (size_t)cg * ND + k0 + sp * 8) = u.v;
    }
    if (is_exp && t < 64) {
        float sg = 0.f, sb = 0.f;
        #pragma unroll 8
        for (int k = 0; k < 32; ++k) {
            sg += T[k][t];
            sb += U[k][t];
        }
        const size_t o = (size_t)(e * 24 + kc) * NCP + c0 + t;
        bpG[o] = sg;
        bpB[o] = sb;
    }
}

// ---------------------------------------------------------------------------
// selector: BM=64, bf16 GEMM xb[64 rows] @ w1bT[128 cols]. TWO 32-k sub-steps
// per barrier (12 rendezvous): A ring-8 (cross-wave safe), B ring-6
// (wave-local), prefetch distance 4 sub-ks, counted vmwait(12/6/0).
// LDS 80 KB; wpart/b1s/w2s alias the A region post-loop.
// ---------------------------------------------------------------------------
__global__ __launch_bounds__(256, 2) void selector_kernel(
    const short* __restrict__ xb, const float* __restrict__ gum,
    const short* __restrict__ w1bT, const float* __restrict__ b1,
    const float* __restrict__ w2, const float* __restrict__ b2,
    u64* __restrict__ counts,
    int* __restrict__ rowlist, int* __restrict__ redolist)
{
    __shared__ __align__(16) char smem[81920];
    short* As = (short*)smem;                    // 8 slabs x 2048 shorts (32 KB)
    short* Bs = (short*)(smem + 32768);          // 6 slabs x 4096 shorts (48 KB)
    float* wpart = (float*)smem;                 // aliased post-loop [4][64][3]
    float* b1s   = (float*)(smem + 3072);        // 128 floats
    float* w2s   = (float*)(smem + 3584);        // 384 floats

    const int t = threadIdx.x;
    const int row0 = blockIdx.x * 64;
    const int w = t >> 6, l = t & 63;
    const int g = l >> 4, lm = l & 15;
    const int sr = t >> 2, sq = t & 3;

    const int aslot = sq ^ ((sr >> 1) & 3);
    const short* axsrc = xb + (size_t)(row0 + sr) * ND + aslot * 8;
    const short* bsrc0 = w1bT + (size_t)(w * 32 +  0 + (l >> 2)) * ND + (l & 3) * 8;
    const short* bsrc1 = w1bT + (size_t)(w * 32 + 16 + (l >> 2)) * ND + (l & 3) * 8;
    const int aoff  = __builtin_amdgcn_readfirstlane(w * 512);
    const int boff0 = __builtin_amdgcn_readfirstlane((w * 32 +  0) * 32);
    const int boff1 = __builtin_amdgcn_readfirstlane((w * 32 + 16) * 32);

    v4f acc[4][2];
    #pragma unroll
    for (int i = 0; i < 4; ++i) { acc[i][0] = (v4f)(0.f); acc[i][1] = (v4f)(0.f); }

    // prologue: sub-ks 0..3
    #pragma unroll
    for (int s = 0; s < 4; ++s) {
        GLD16(axsrc + s * 32, As + s * 2048 + aoff);
        GLD16(bsrc0 + s * 32, Bs + s * 4096 + boff0);
        GLD16(bsrc1 + s * 32, Bs + s * 4096 + boff1);
    }

    #pragma unroll
    for (int S = 0; S < 12; ++S) {
        if (S <= 9) {
            #pragma unroll
            for (int u = 0; u < 2; ++u) {
                const int j = 2 * S + 4 + u;
                GLD16(axsrc + j * 32, As + (j & 7) * 2048 + aoff);
                GLD16(bsrc0 + j * 32, Bs + (j % 6) * 4096 + boff0);
                GLD16(bsrc1 + j * 32, Bs + (j % 6) * 4096 + boff1);
            }
            vmwait(12);
        } else if (S == 10) {
            vmwait(6);
        } else {
            vmwait(0);
        }
        __builtin_amdgcn_sched_barrier(0);
        __builtin_amdgcn_s_barrier();          // sub-ks {2S,2S+1} landed

        #pragma unroll
        for (int u = 0; u < 2; ++u) {
            const int j = 2 * S + u;
            const short* Aj = As + (j & 7) * 2048;
            const short* Bj = Bs + (j % 6) * 4096;
            v8s af[4];
            #pragma unroll
            for (int mf = 0; mf < 4; ++mf) {
                const int row = mf * 16 + lm;
                af[mf] = *(const v8s*)&Aj[row * 32 + (g ^ ((lm >> 1) & 3)) * 8];
            }
            #pragma unroll
            for (int nf = 0; nf < 2; ++nf) {
                const int cl = w * 32 + nf * 16 + lm;
                const v8s bv = *(const v8s*)&Bj[cl * 32 + (g ^ ((lm >> 1) & 3)) * 8];
                #pragma unroll
                for (int mf = 0; mf < 4; ++mf)
                    acc[mf][nf] = __builtin_amdgcn_mfma_f32_16x16x32_bf16(
                        af[mf], bv, acc[mf][nf], 0, 0, 0);
            }
        }
        asm volatile("s_waitcnt lgkmcnt(0)" ::: "memory");
        __builtin_amdgcn_sched_barrier(0);
    }

    __syncthreads();   // all MFMA LDS reads complete before aliasing A region
    if (t < NH) {
        b1s[t] = b1[t];
        w2s[t*3+0] = w2[t*3+0]; w2s[t*3+1] = w2[t*3+1]; w2s[t*3+2] = w2[t*3+2];
    }
    __syncthreads();

    // logit partials: relu(h + b1) @ w2 over this wave's 32 cols
    #pragma unroll
    for (int mf = 0; mf < 4; ++mf) {
        float p[4][3] = {};
        #pragma unroll
        for (int nf = 0; nf < 2; ++nf) {
            const int cl = w * 32 + nf * 16 + lm;
            const float bb = b1s[cl];
            const float wa = w2s[cl*3], wb = w2s[cl*3+1], wc = w2s[cl*3+2];
            #pragma unroll
            for (int r = 0; r < 4; ++r) {
                const float h = fmaxf(acc[mf][nf][r] + bb, 0.f);
                p[r][0] = fmaf(h, wa, p[r][0]);
                p[r][1] = fmaf(h, wb, p[r][1]);
                p[r][2] = fmaf(h, wc, p[r][2]);
            }
        }
        #pragma unroll
        for (int m = 1; m < 16; m <<= 1)
            #pragma unroll
            for (int r = 0; r < 4; ++r) {
                p[r][0] += __shfl_xor(p[r][0], m);
                p[r][1] += __shfl_xor(p[r][1], m);
                p[r][2] += __shfl_xor(p[r][2], m);
            }
        if (lm == 0) {
            #pragma unroll
            for (int r = 0; r < 4; ++r) {
                const int row = mf * 16 + g * 4 + r;
                wpart[(w * 64 + row) * 3 + 0] = p[r][0];
                wpart[(w * 64 + row) * 3 + 1] = p[r][1];
                wpart[(w * 64 + row) * 3 + 2] = p[r][2];
            }
        }
    }
    __syncthreads();

    if (t < 64) {
        const int grow = row0 + l;
        const float z0 = wpart[(0*64+l)*3+0] + wpart[(1*64+l)*3+0]
                       + wpart[(2*64+l)*3+0] + wpart[(3*64+l)*3+0]
                       + b2[0] + gum[grow*3+0];
        const float z1 = wpart[(0*64+l)*3+1] + wpart[(1*64+l)*3+1]
                       + wpart[(2*64+l)*3+1] + wpart[(3*64+l)*3+1]
                       + b2[1] + gum[grow*3+1];
        const float z2 = wpart[(0*64+l)*3+2] + wpart[(1*64+l)*3+2]
                       + wpart[(2*64+l)*3+2] + wpart[(3*64+l)*3+2]
                       + b2[2] + gum[grow*3+2];
        int be = 0; float best = z0;
        if (z1 > best) { best = z1; be = 1; }
        if (z2 > best) { best = z2; be = 2; }
        const float second = (be==0) ? fmaxf(z1,z2) : (be==1) ? fmaxf(z0,z2) : fmaxf(z0,z1);
        if (best - second < GAP_THR) be = 3;

        const u64 m0 = __ballot(be == 0);
        const u64 m1 = __ballot(be == 1);
        const u64 m2 = __ballot(be == 2);
        const u64 m3 = __ballot(be == 3);
        u64 old = 0;
        if (l == 0) {
            const u64 add = (u64)__popcll(m0)
                          | ((u64)__popcll(m1) << 16)
                          | ((u64)__popcll(m2) << 32)
                          | ((u64)__popcll(m3) << 48);
            old = atomicAdd(counts, add);
        }
        const int blo = __shfl((int)(old & 0xFFFFFFFFull), 0);
        const int bhi = __shfl((int)(old >> 32), 0);
        old = ((u64)(unsigned)bhi << 32) | (u64)(unsigned)blo;
        const u64 mym = (be == 0) ? m0 : (be == 1) ? m1 : (be == 2) ? m2 : m3;
        const u64 below = (l == 63) ? 0x7FFFFFFFFFFFFFFFull : ((1ull << l) - 1ull);
        const int rank = __popcll(mym & below);
        const int base = (int)((old >> (16 * be)) & 0xFFFFull);
        const int idx = base + rank;
        if (be < 3) {
            if ((unsigned)idx < NB) rowlist[be * NB + idx] = grow;
        } else {
            if ((unsigned)idx < NB) redolist[idx] = grow;
        }
    }
}

// fp64 redo for ambiguous rows
__global__ __launch_bounds__(128) void redo_kernel(
    const float* __restrict__ x, const float* __restrict__ gum,
    const float* __restrict__ w1, const float* __restrict__ b1,
    const float* __restrict__ w2, const float* __restrict__ b2,
    u64* __restrict__ counts, int* __restrict__ rowlist,
    const int* __restrict__ redolist)
{
    const int t = threadIdx.x;
    int n = (int)((*counts >> 48) & 0xFFFFull);
    if (n > NB) n = NB;
    __shared__ float xs[ND];
    __shared__ double red[2][3];
    for (int i = blockIdx.x; i < n; i += gridDim.x) {
        const int row = redolist[i];
        {
            const float4* xp = (const float4*)(x + (size_t)row * ND);
            float4* xsv = (float4*)xs;
            xsv[t] = xp[t];
            if (t < 64) xsv[128 + t] = xp[128 + t];
        }
        __syncthreads();
        double h0 = 0.0, h1 = 0.0, h2 = 0.0, h3 = 0.0;
        double h4 = 0.0, h5 = 0.0, h6 = 0.0, h7 = 0.0;
        #pragma unroll 2
        for (int k = 0; k < ND; k += 8) {
            const float w0 = w1[(size_t)(k+0) * NH + t];
            const float w1v = w1[(size_t)(k+1) * NH + t];
            const float w2v = w1[(size_t)(k+2) * NH + t];
            const float w3 = w1[(size_t)(k+3) * NH + t];
            const float w4 = w1[(size_t)(k+4) * NH + t];
            const float w5 = w1[(size_t)(k+5) * NH + t];
            const float w6 = w1[(size_t)(k+6) * NH + t];
            const float w7 = w1[(size_t)(k+7) * NH + t];
            h0 = fma((double)xs[k+0], (double)w0, h0);
            h1 = fma((double)xs[k+1], (double)w1v, h1);
            h2 = fma((double)xs[k+2], (double)w2v, h2);
            h3 = fma((double)xs[k+3], (double)w3, h3);
            h4 = fma((double)xs[k+4], (double)w4, h4);
            h5 = fma((double)xs[k+5], (double)w5, h5);
            h6 = fma((double)xs[k+6], (double)w6, h6);
            h7 = fma((double)xs[k+7], (double)w7, h7);
        }
        double h = (((h0 + h1) + (h2 + h3)) + ((h4 + h5) + (h6 + h7)))
                 + (double)b1[t];
        h = h > 0.0 ? h : 0.0;
        double p0 = h * (double)w2[t * 3 + 0];
        double p1 = h * (double)w2[t * 3 + 1];
        double p2 = h * (double)w2[t * 3 + 2];
        #pragma unroll
        for (int m = 32; m >= 1; m >>= 1) {
            p0 += __shfl_xor(p0, m);
            p1 += __shfl_xor(p1, m);
            p2 += __shfl_xor(p2, m);
        }
        if ((t & 63) == 0) {
            red[t >> 6][0] = p0; red[t >> 6][1] = p1; red[t >> 6][2] = p2;
        }
        __syncthreads();
        if (t == 0) {
            double best = 0.0; int be = 0;
            #pragma unroll
            for (int e = 0; e < NE; ++e) {
                const double z = red[0][e] + red[1][e] + (double)b2[e]
                               + (double)gum[(size_t)row * 3 + e];
                if (e == 0 || z > best) { best = z; be = e; }
            }
            const u64 old = atomicAdd(counts, 1ull << (16 * be));
            const int pos = (int)((old >> (16 * be)) & 0xFFFFull);
            if ((unsigned)pos < NB) rowlist[be * NB + pos] = row;
        }
        __syncthreads();
    }
}

// ---------------------------------------------------------------------------
// head: R20 pipeline (best measured: ~70 us). BM=64 x BN=256. A (HBM,
// cross-wave) = ring-4 depth-2; B (L2-hot, wave-local) = dbuf depth-1.
// ONE barrier per step, after the counted vmwait (6 / 5 / 0 tail).
// Preamble sums the 24 bias partials (hb + bpB / bpG) into hbs/css.
// ---------------------------------------------------------------------------
__global__ __launch_bounds__(256, 3) void head_kernel(
    const short* __restrict__ xb, const float2* __restrict__ murs,
    const short* __restrict__ hwbT, const float* __restrict__ hb,
    const float* __restrict__ bpB, const float* __restrict__ bpG,
    const u64* __restrict__ counts, const int* __restrict__ rowlist,
    float* __restrict__ out)
{
    const int e = blockIdx.z;
    int cnt = (int)((*counts >> (16 * e)) & 0xFFFFull);
    if (cnt > NB) cnt = NB;
    const int rc0 = blockIdx.y * 64;
    if (rc0 >= cnt) return;
    const int n0 = blockIdx.x * 256;

    __shared__ __align__(16) short As[4][2048];      // ring-4: 64 rows x 32k
    __shared__ __align__(16) short Bs[2][8192];      // dbuf: 256c x 32k
    __shared__ float hbs[256], css[256], rs_s[64], rm_s[64];
    __shared__ int rows_s[64];

    const int t = threadIdx.x;
    const int w = t >> 6, l = t & 63;
    const int g = l >> 4, lm = l & 15;
    const int sr = t >> 2, sq = t & 3;

    if (t < 64) {
        const int ri = rc0 + t;
        int rr = (ri < cnt) ? rowlist[e * NB + ri] : -1;
        if (rr >= NB) rr = -1;
        rows_s[t] = rr;
        const float2 mr = (rr >= 0) ? murs[rr] : make_float2(0.f, 0.f);
        rs_s[t] = mr.y;
        rm_s[t] = mr.y * mr.x;   // rs*mu
    }
    {
        float sb = (n0 + t < NC) ? hb[e * NC + n0 + t] : 0.f;
        float sg = 0.f;
        #pragma unroll 4
        for (int kc = 0; kc < 24; ++kc) {
            sb += bpB[(size_t)(e * 24 + kc) * NCP + n0 + t];
            sg += bpG[(size_t)(e * 24 + kc) * NCP + n0 + t];
        }
        hbs[t] = sb;
        css[t] = sg;
    }

    const int ridx = rc0 + sr;
    int arow = (ridx < cnt) ? rowlist[e * NB + ridx] : 0;
    if ((unsigned)arow >= NB) arow = 0;
    const int aslot = sq ^ ((sr >> 1) & 3);
    const short* axsrc = xb + (size_t)arow * ND + aslot * 8;
    const short* hwe = hwbT + (size_t)e * NCP * ND + (size_t)n0 * ND;
    const int aoff = __builtin_amdgcn_readfirstlane(w * 512);

    v4f acc[4][4];
    #pragma unroll
    for (int i = 0; i < 4; ++i)
        #pragma unroll
        for (int j = 0; j < 4; ++j) acc[i][j] = (v4f)(0.f);

    // prologue: B(0)x4, then A(0), A(1). (__syncthreads drains them once.)
    #pragma unroll
    for (int i = 0; i < 4; ++i) {
        const int crow = w * 64 + i * 16 + (l >> 2);
        const int off = __builtin_amdgcn_readfirstlane((w * 64 + i * 16) * 32);
        GLD16(hwe + (size_t)crow * ND + (l & 3) * 8, &Bs[0][0] + off);
    }
    GLD16(axsrc,      &As[0][0] + aoff);
    GLD16(axsrc + 32, &As[1][0] + aoff);
    __syncthreads();   // rows_s/hbs visible; prologue loads landed

    #pragma unroll
    for (int ks = 0; ks < 24; ++ks) {
        const int curA = ks & 3;
        const int curB = ks & 1;
        if (ks < 23) {
            #pragma unroll
            for (int i = 0; i < 4; ++i) {
                const int crow = w * 64 + i * 16 + (l >> 2);
                const int off = __builtin_amdgcn_readfirstlane((w * 64 + i * 16) * 32);
                GLD16(hwe + (size_t)crow * ND + (ks + 1) * 32 + (l & 3) * 8,
                      &Bs[(ks + 1) & 1][0] + off);
            }
        }
        if (ks < 22) {
            GLD16(axsrc + (ks + 2) * 32, &As[(ks + 2) & 3][0] + aoff);
        }
        if (ks < 22)       vmwait(6);
        else if (ks == 22) vmwait(5);
        else               vmwait(0);
        __builtin_amdgcn_sched_barrier(0);
        __builtin_amdgcn_s_barrier();          // stage ks landed everywhere

        v8s af[4];
        #pragma unroll
        for (int mf = 0; mf < 4; ++mf) {
            const int row = mf * 16 + lm;
            af[mf] = *(const v8s*)&As[curA][row * 32 + (g ^ ((lm >> 1) & 3)) * 8];
        }
        #pragma unroll
        for (int nf = 0; nf < 4; ++nf) {
            const int cl = w * 64 + nf * 16 + lm;
            const v8s bv = *(const v8s*)&Bs[curB][cl * 32 + (g ^ ((lm >> 1) & 3)) * 8];
            #pragma unroll
            for (int mf = 0; mf < 4; ++mf)
                acc[mf][nf] = __builtin_amdgcn_mfma_f32_16x16x32_bf16(
                    af[mf], bv, acc[mf][nf], 0, 0, 0);
        }
        asm volatile("s_waitcnt lgkmcnt(0)" ::: "memory");
        __builtin_amdgcn_sched_barrier(0);
    }

    #pragma unroll
    for (int mf = 0; mf < 4; ++mf) {
        #pragma unroll
        for (int r = 0; r < 4; ++r) {
            const int rl = mf * 16 + g * 4 + r;
            const int orow = rows_s[rl];
            if (orow < 0) continue;
            const float rs = rs_s[rl], rm = rm_s[rl];
            float* op = out + (size_t)orow * NC;
            #pragma unroll
            for (int nf = 0; nf < 4; ++nf) {
                const int cl = w * 64 + nf * 16 + lm;
                const int c = n0 + cl;
                if (c < NC)
                    op[c] = acc[mf][nf][r] * rs - rm * css[cl] + hbs[cl];
            }
        }
    }
}

extern "C" void kernel_launch(void* const* d_in, const int* in_sizes, int n_in,
                              void* d_out, int out_size, void* d_ws, size_t ws_size,
                              hipStream_t stream) {
    const float* x     = (const float*)d_in[0];
    const float* gum   = (const float*)d_in[1];
    const float* w1    = (const float*)d_in[2];
    const float* b1    = (const float*)d_in[3];
    const float* w2    = (const float*)d_in[4];
    const float* b2    = (const float*)d_in[5];
    const float* gamma = (const float*)d_in[6];
    const float* beta  = (const float*)d_in[7];
    const float* hw    = (const float*)d_in[8];
    const float* hb    = (const float*)d_in[9];
    float* out = (float*)d_out;

    char* ws = (char*)d_ws;
    u64*    counts   = (u64*)ws;                    // packed 4x16-bit counters
    float2* murs     = (float2*)(ws + 256);         // 262144 B
    int*    rowlist  = (int*)(ws + 262400);         // 393216 B
    int*    redolist = (int*)(ws + 655616);         // 131072 B
    float*  bpB      = (float*)(ws + 786688);       // 147456 B (per-chunk partials)
    float*  bpG      = (float*)(ws + 934144);       // 147456 B
    short*  w1bT     = (short*)(ws + 1081600);      // 196608 B
    short*  hwbT     = (short*)(ws + 1278208);      // 2359296 B -> 3637504
    short*  xbg      = (short*)(ws + XB_OFF);       // 50 MB

    pre_kernel<<<624 + NB / 16, 256, 0, stream>>>(
        hw, gamma, beta, w1, x, hwbT, w1bT, bpB, bpG, murs, xbg, counts);
    selector_kernel<<<NB / 64, 256, 0, stream>>>(xbg, gum, w1bT, b1, w2, b2,
                                                 counts, rowlist, redolist);
    redo_kernel<<<1024, 128, 0, stream>>>(x, gum, w1, b1, w2, b2,
                                          counts, rowlist, redolist);
    head_kernel<<<dim3(2, NB / 64, NE), 256, 0, stream>>>(
        xbg, murs, hwbT, hb, bpB, bpG, counts, rowlist, out);
}

// Round 23
// 134.123 us; speedup vs baseline: 1.0606x; 1.0606x over previous
//
#include <hip/hip_runtime.h>
#include <hip/hip_bf16.h>
#include <math.h>

#define NB 32768
#define ND 768
#define NC 474
#define NCP 512
#define NE 3
#define NH 128
#define GAP_THR 0.035f
#define XB_OFF 4194304ull

typedef short v8s __attribute__((ext_vector_type(8)));
typedef float v4f __attribute__((ext_vector_type(4)));
typedef unsigned long long u64;

#define GLD16(gp, lp) __builtin_amdgcn_global_load_lds( \
    (const __attribute__((address_space(1))) void*)(gp), \
    (__attribute__((address_space(3))) void*)(lp), 16, 0, 0)

static __device__ __forceinline__ short f2bf(float f) {
    __hip_bfloat16 h = __float2bfloat16(f);
    return *reinterpret_cast<short*>(&h);
}

static __device__ __forceinline__ void vmwait(int n) {
    switch (n) {
    case 0:  asm volatile("s_waitcnt vmcnt(0)"  ::: "memory"); break;
    case 4:  asm volatile("s_waitcnt vmcnt(4)"  ::: "memory"); break;
    case 5:  asm volatile("s_waitcnt vmcnt(5)"  ::: "memory"); break;
    case 6:  asm volatile("s_waitcnt vmcnt(6)"  ::: "memory"); break;
    case 8:  asm volatile("s_waitcnt vmcnt(8)"  ::: "memory"); break;
    default: asm volatile("s_waitcnt vmcnt(10)" ::: "memory"); break;
    }
}

// ---------------------------------------------------------------------------
// prep (+fused bias reduce): hwbT[e][c][k] = bf16(gamma*hw) transposed +
// slot-swizzled; w1bT likewise from w1. Expert blocks atomically accumulate
// csumv += sum_k gamma*hw, hbias += sum_k beta*hw (+hb once via kc==0).
// Block 0 zeroes counts. hbias/csumv memset before this kernel.
// ---------------------------------------------------------------------------
__global__ __launch_bounds__(256) void prep_kernel(
    const float* __restrict__ hw, const float* __restrict__ gamma,
    const float* __restrict__ beta, const float* __restrict__ w1,
    const float* __restrict__ hb,
    short* __restrict__ hwbT, short* __restrict__ w1bT,
    float* __restrict__ hbias, float* __restrict__ csumv,
    u64* __restrict__ counts)
{
    __shared__ float T[32][72];
    __shared__ float U[32][72];
    const int t = threadIdx.x;
    const int id = blockIdx.x;
    if (id == 0 && t == 0) *counts = 0ull;
    const float* src; short* dst; int stride, ncs; int e = 0, cc, kc;
    bool is_exp = (id < 576);
    if (is_exp) {
        e = id / 192; const int r2 = id % 192; cc = r2 / 24; kc = r2 % 24;
        src = hw + (size_t)e * ND * NC; stride = NC; ncs = NC;
        dst = hwbT + (size_t)e * NCP * ND;
    } else {
        const int j = id - 576; cc = j / 24; kc = j % 24;
        src = w1; stride = NH; ncs = NH; dst = w1bT;
    }
    const int c0 = cc * 64, k0 = kc * 32;
    {
        const int kl = t >> 3, c8 = (t & 7) * 8;
        const float g  = is_exp ? gamma[e * ND + k0 + kl] : 1.f;
        const float bb = is_exp ? beta[e * ND + k0 + kl]  : 0.f;
        #pragma unroll
        for (int j = 0; j < 8; ++j) {
            const int cg = c0 + c8 + j;
            const float v = (cg < ncs) ? src[(size_t)(k0 + kl) * stride + cg] : 0.f;
            T[kl][c8 + j] = v * g;
            U[kl][c8 + j] = v * bb;
        }
    }
    __syncthreads();
    {
        const int cl = t >> 2, q = t & 3;
        const int cg = c0 + cl;
        const int sp = q ^ ((cg >> 1) & 3);
        union { short s[8]; int4 v; } u;
        #pragma unroll
        for (int j = 0; j < 8; ++j) u.s[j] = f2bf(T[q * 8 + j][cl]);
        *(int4*)(dst + (size_t)cg * ND + k0 + sp * 8) = u.v;
    }
    if (is_exp && t < 64) {
        float sg = 0.f, sb = 0.f;
        #pragma unroll 8
        for (int k = 0; k < 32; ++k) {
            sg += T[k][t];
            sb += U[k][t];
        }
        const int c = c0 + t;
        if (kc == 0 && c < NC) sb += hb[e * NC + c];
        atomicAdd(&csumv[e * NCP + c], sg);
        atomicAdd(&hbias[e * NCP + c], sb);
    }
}

// ---------------------------------------------------------------------------
// lnsel: FUSED ln_convert + selector. 64 rows/block (512 blocks = 2/CU).
// Per thread: row sr, k-chunk sq*8 of each 32-k sub-k. Loads x fp32 directly
// (1-superstep reg pipeline), cvt -> ds_write A-slab (ring-8) + store xb;
// LN stats on the same regs. B via GLD16 ring-6 (wave-local). Two sub-k per
// barrier, counted vmwait includes the xb stores (steady 10, tail 6/4).
// Epilogue: logits + gap cascade + packed-atomic append; LDS aliased.
// ---------------------------------------------------------------------------
__global__ __launch_bounds__(256, 2) void lnsel_kernel(
    const float* __restrict__ x, const float* __restrict__ gum,
    const short* __restrict__ w1bT, const float* __restrict__ b1,
    const float* __restrict__ w2, const float* __restrict__ b2,
    float2* __restrict__ murs, short* __restrict__ xb,
    u64* __restrict__ counts,
    int* __restrict__ rowlist, int* __restrict__ redolist)
{
    __shared__ __align__(16) char smem[81920];
    short* As = (short*)smem;                    // 8 slabs x 2048 shorts (32 KB)
    short* Bs = (short*)(smem + 32768);          // 6 slabs x 4096 shorts (48 KB)
    float* wpart = (float*)smem;                 // aliased post-loop [4][64][3]
    float* b1s   = (float*)(smem + 3072);        // 128 floats
    float* w2s   = (float*)(smem + 3584);        // 384 floats

    const int t = threadIdx.x;
    const int row0 = blockIdx.x * 64;
    const int w = t >> 6, l = t & 63;
    const int g = l >> 4, lm = l & 15;
    const int sr = t >> 2, sq = t & 3;

    const int aslot = sq ^ ((sr >> 1) & 3);
    const int awr = sr * 32 + aslot * 8;         // ds_write offset (shorts)
    const float* xrow = x + (size_t)(row0 + sr) * ND + sq * 8;
    short* xo = xb + (size_t)(row0 + sr) * ND + sq * 8;
    const short* bsrc0 = w1bT + (size_t)(w * 32 +  0 + (l >> 2)) * ND + (l & 3) * 8;
    const short* bsrc1 = w1bT + (size_t)(w * 32 + 16 + (l >> 2)) * ND + (l & 3) * 8;
    const int boff0 = __builtin_amdgcn_readfirstlane((w * 32 +  0) * 32);
    const int boff1 = __builtin_amdgcn_readfirstlane((w * 32 + 16) * 32);

    v4f acc[4][2];
    #pragma unroll
    for (int i = 0; i < 4; ++i) { acc[i][0] = (v4f)(0.f); acc[i][1] = (v4f)(0.f); }
    float s1 = 0.f, s2 = 0.f;

    auto cvst = [&](float4 a, float4 b, int j) {
        s1 += a.x + a.y + a.z + a.w + b.x + b.y + b.z + b.w;
        s2 += a.x*a.x + a.y*a.y + a.z*a.z + a.w*a.w
            + b.x*b.x + b.y*b.y + b.z*b.z + b.w*b.w;
        v8s v;
        v[0]=f2bf(a.x); v[1]=f2bf(a.y); v[2]=f2bf(a.z); v[3]=f2bf(a.w);
        v[4]=f2bf(b.x); v[5]=f2bf(b.y); v[6]=f2bf(b.z); v[7]=f2bf(b.w);
        *(v8s*)&As[(j & 7) * 2048 + awr] = v;
        *(v8s*)(xo + j * 32) = v;
    };

    // ---- prologue: x j0..3 loads, B j0..3 GLD16, cvt j0,1; keep j2,3 ----
    float4 q0 = *(const float4*)(xrow + 0);
    float4 q1 = *(const float4*)(xrow + 4);
    float4 q2 = *(const float4*)(xrow + 32);
    float4 q3 = *(const float4*)(xrow + 36);
    float4 cA0 = *(const float4*)(xrow + 64);
    float4 cA1 = *(const float4*)(xrow + 68);
    float4 cB0 = *(const float4*)(xrow + 96);
    float4 cB1 = *(const float4*)(xrow + 100);
    #pragma unroll
    for (int j = 0; j < 4; ++j) {
        GLD16(bsrc0 + j * 32, Bs + j * 4096 + boff0);
        GLD16(bsrc1 + j * 32, Bs + j * 4096 + boff1);
    }
    __builtin_amdgcn_sched_barrier(0);
    vmwait(8);                                   // x j0..3 landed
    __builtin_amdgcn_sched_barrier(0);
    cvst(q0, q1, 0);
    cvst(q2, q3, 1);

    #pragma unroll
    for (int S = 0; S < 12; ++S) {
        float4 pA0, pA1, pB0, pB1;
        if (S <= 9) {
            const int j4 = 2 * S + 4;
            pA0 = *(const float4*)(xrow + j4 * 32);
            pA1 = *(const float4*)(xrow + j4 * 32 + 4);
            pB0 = *(const float4*)(xrow + j4 * 32 + 32);
            pB1 = *(const float4*)(xrow + j4 * 32 + 36);
            GLD16(bsrc0 + j4 * 32,        Bs + (j4 % 6) * 4096 + boff0);
            GLD16(bsrc1 + j4 * 32,        Bs + (j4 % 6) * 4096 + boff1);
            GLD16(bsrc0 + (j4 + 1) * 32,  Bs + ((j4 + 1) % 6) * 4096 + boff0);
            GLD16(bsrc1 + (j4 + 1) * 32,  Bs + ((j4 + 1) % 6) * 4096 + boff1);
            __builtin_amdgcn_sched_barrier(0);
            vmwait(10);     // drain prev step's {stores,x,B}; keep cur 8 + 2 stores
        } else if (S == 10) {
            vmwait(6);      // x(j22,23) landed
        } else {
            vmwait(4);      // B(j22,23) landed
        }
        __builtin_amdgcn_sched_barrier(0);
        if (S <= 10) {
            cvst(cA0, cA1, 2 * S + 2);
            cvst(cB0, cB1, 2 * S + 3);
        }
        if (S <= 9) { cA0 = pA0; cA1 = pA1; cB0 = pB0; cB1 = pB1; }
        asm volatile("s_waitcnt lgkmcnt(0)" ::: "memory");   // ds_writes visible
        __builtin_amdgcn_sched_barrier(0);
        __builtin_amdgcn_s_barrier();            // A(j=2S,2S+1) visible to all

        #pragma unroll
        for (int u = 0; u < 2; ++u) {
            const int j = 2 * S + u;
            const short* Aj = As + (j & 7) * 2048;
            const short* Bj = Bs + (j % 6) * 4096;
            v8s af[4];
            #pragma unroll
            for (int mf = 0; mf < 4; ++mf) {
                const int row = mf * 16 + lm;
                af[mf] = *(const v8s*)&Aj[row * 32 + (g ^ ((lm >> 1) & 3)) * 8];
            }
            #pragma unroll
            for (int nf = 0; nf < 2; ++nf) {
                const int cl = w * 32 + nf * 16 + lm;
                const v8s bv = *(const v8s*)&Bj[cl * 32 + (g ^ ((lm >> 1) & 3)) * 8];
                #pragma unroll
                for (int mf = 0; mf < 4; ++mf)
                    acc[mf][nf] = __builtin_amdgcn_mfma_f32_16x16x32_bf16(
                        af[mf], bv, acc[mf][nf], 0, 0, 0);
            }
        }
        asm volatile("s_waitcnt lgkmcnt(0)" ::: "memory");
        __builtin_amdgcn_sched_barrier(0);
    }

    // LN stats: reduce over the 4 threads of each row, write murs
    {
        float r1 = s1 + __shfl_xor(s1, 1);
        float r2 = s2 + __shfl_xor(s2, 1);
        r1 += __shfl_xor(r1, 2);
        r2 += __shfl_xor(r2, 2);
        if (sq == 0) {
            const float mu = r1 * (1.f / 768.f);
            const float var = r2 * (1.f / 768.f) - mu * mu;
            murs[row0 + sr] = make_float2(mu, rsqrtf(var + 1e-5f));
        }
    }

    __syncthreads();   // all MFMA LDS reads complete before aliasing A region
    if (t < NH) {
        b1s[t] = b1[t];
        w2s[t*3+0] = w2[t*3+0]; w2s[t*3+1] = w2[t*3+1]; w2s[t*3+2] = w2[t*3+2];
    }
    __syncthreads();

    // logit partials: relu(h + b1) @ w2 over this wave's 32 cols
    #pragma unroll
    for (int mf = 0; mf < 4; ++mf) {
        float p[4][3] = {};
        #pragma unroll
        for (int nf = 0; nf < 2; ++nf) {
            const int cl = w * 32 + nf * 16 + lm;
            const float bb = b1s[cl];
            const float wa = w2s[cl*3], wb = w2s[cl*3+1], wc = w2s[cl*3+2];
            #pragma unroll
            for (int r = 0; r < 4; ++r) {
                const float h = fmaxf(acc[mf][nf][r] + bb, 0.f);
                p[r][0] = fmaf(h, wa, p[r][0]);
                p[r][1] = fmaf(h, wb, p[r][1]);
                p[r][2] = fmaf(h, wc, p[r][2]);
            }
        }
        #pragma unroll
        for (int m = 1; m < 16; m <<= 1)
            #pragma unroll
            for (int r = 0; r < 4; ++r) {
                p[r][0] += __shfl_xor(p[r][0], m);
                p[r][1] += __shfl_xor(p[r][1], m);
                p[r][2] += __shfl_xor(p[r][2], m);
            }
        if (lm == 0) {
            #pragma unroll
            for (int r = 0; r < 4; ++r) {
                const int row = mf * 16 + g * 4 + r;
                wpart[(w * 64 + row) * 3 + 0] = p[r][0];
                wpart[(w * 64 + row) * 3 + 1] = p[r][1];
                wpart[(w * 64 + row) * 3 + 2] = p[r][2];
            }
        }
    }
    __syncthreads();

    if (t < 64) {
        const int grow = row0 + l;
        const float z0 = wpart[(0*64+l)*3+0] + wpart[(1*64+l)*3+0]
                       + wpart[(2*64+l)*3+0] + wpart[(3*64+l)*3+0]
                       + b2[0] + gum[grow*3+0];
        const float z1 = wpart[(0*64+l)*3+1] + wpart[(1*64+l)*3+1]
                       + wpart[(2*64+l)*3+1] + wpart[(3*64+l)*3+1]
                       + b2[1] + gum[grow*3+1];
        const float z2 = wpart[(0*64+l)*3+2] + wpart[(1*64+l)*3+2]
                       + wpart[(2*64+l)*3+2] + wpart[(3*64+l)*3+2]
                       + b2[2] + gum[grow*3+2];
        int be = 0; float best = z0;
        if (z1 > best) { best = z1; be = 1; }
        if (z2 > best) { best = z2; be = 2; }
        const float second = (be==0) ? fmaxf(z1,z2) : (be==1) ? fmaxf(z0,z2) : fmaxf(z0,z1);
        if (best - second < GAP_THR) be = 3;

        const u64 m0 = __ballot(be == 0);
        const u64 m1 = __ballot(be == 1);
        const u64 m2 = __ballot(be == 2);
        const u64 m3 = __ballot(be == 3);
        u64 old = 0;
        if (l == 0) {
            const u64 add = (u64)__popcll(m0)
                          | ((u64)__popcll(m1) << 16)
                          | ((u64)__popcll(m2) << 32)
                          | ((u64)__popcll(m3) << 48);
            old = atomicAdd(counts, add);
        }
        const int blo = __shfl((int)(old & 0xFFFFFFFFull), 0);
        const int bhi = __shfl((int)(old >> 32), 0);
        old = ((u64)(unsigned)bhi << 32) | (u64)(unsigned)blo;
        const u64 mym = (be == 0) ? m0 : (be == 1) ? m1 : (be == 2) ? m2 : m3;
        const u64 below = (l == 63) ? 0x7FFFFFFFFFFFFFFFull : ((1ull << l) - 1ull);
        const int rank = __popcll(mym & below);
        const int base = (int)((old >> (16 * be)) & 0xFFFFull);
        const int idx = base + rank;
        if (be < 3) {
            if ((unsigned)idx < NB) rowlist[be * NB + idx] = grow;
        } else {
            if ((unsigned)idx < NB) redolist[idx] = grow;
        }
    }
}

// fp64 redo for ambiguous rows
__global__ __launch_bounds__(128) void redo_kernel(
    const float* __restrict__ x, const float* __restrict__ gum,
    const float* __restrict__ w1, const float* __restrict__ b1,
    const float* __restrict__ w2, const float* __restrict__ b2,
    u64* __restrict__ counts, int* __restrict__ rowlist,
    const int* __restrict__ redolist)
{
    const int t = threadIdx.x;
    int n = (int)((*counts >> 48) & 0xFFFFull);
    if (n > NB) n = NB;
    __shared__ float xs[ND];
    __shared__ double red[2][3];
    for (int i = blockIdx.x; i < n; i += gridDim.x) {
        const int row = redolist[i];
        {
            const float4* xp = (const float4*)(x + (size_t)row * ND);
            float4* xsv = (float4*)xs;
            xsv[t] = xp[t];
            if (t < 64) xsv[128 + t] = xp[128 + t];
        }
        __syncthreads();
        double h0 = 0.0, h1 = 0.0, h2 = 0.0, h3 = 0.0;
        double h4 = 0.0, h5 = 0.0, h6 = 0.0, h7 = 0.0;
        #pragma unroll 2
        for (int k = 0; k < ND; k += 8) {
            const float w0 = w1[(size_t)(k+0) * NH + t];
            const float w1v = w1[(size_t)(k+1) * NH + t];
            const float w2v = w1[(size_t)(k+2) * NH + t];
            const float w3 = w1[(size_t)(k+3) * NH + t];
            const float w4 = w1[(size_t)(k+4) * NH + t];
            const float w5 = w1[(size_t)(k+5) * NH + t];
            const float w6 = w1[(size_t)(k+6) * NH + t];
            const float w7 = w1[(size_t)(k+7) * NH + t];
            h0 = fma((double)xs[k+0], (double)w0, h0);
            h1 = fma((double)xs[k+1], (double)w1v, h1);
            h2 = fma((double)xs[k+2], (double)w2v, h2);
            h3 = fma((double)xs[k+3], (double)w3, h3);
            h4 = fma((double)xs[k+4], (double)w4, h4);
            h5 = fma((double)xs[k+5], (double)w5, h5);
            h6 = fma((double)xs[k+6], (double)w6, h6);
            h7 = fma((double)xs[k+7], (double)w7, h7);
        }
        double h = (((h0 + h1) + (h2 + h3)) + ((h4 + h5) + (h6 + h7)))
                 + (double)b1[t];
        h = h > 0.0 ? h : 0.0;
        double p0 = h * (double)w2[t * 3 + 0];
        double p1 = h * (double)w2[t * 3 + 1];
        double p2 = h * (double)w2[t * 3 + 2];
        #pragma unroll
        for (int m = 32; m >= 1; m >>= 1) {
            p0 += __shfl_xor(p0, m);
            p1 += __shfl_xor(p1, m);
            p2 += __shfl_xor(p2, m);
        }
        if ((t & 63) == 0) {
            red[t >> 6][0] = p0; red[t >> 6][1] = p1; red[t >> 6][2] = p2;
        }
        __syncthreads();
        if (t == 0) {
            double best = 0.0; int be = 0;
            #pragma unroll
            for (int e = 0; e < NE; ++e) {
                const double z = red[0][e] + red[1][e] + (double)b2[e]
                               + (double)gum[(size_t)row * 3 + e];
                if (e == 0 || z > best) { best = z; be = e; }
            }
            const u64 old = atomicAdd(counts, 1ull << (16 * be));
            const int pos = (int)((old >> (16 * be)) & 0xFFFFull);
            if ((unsigned)pos < NB) rowlist[be * NB + pos] = row;
        }
        __syncthreads();
    }
}

// ---------------------------------------------------------------------------
// head: R20/R21 pipeline (best measured ~70 us). BM=64 x BN=256. A (HBM,
// cross-wave) = ring-4 depth-2; B (L2-hot, wave-local) = dbuf depth-1.
// ONE barrier per step, after the counted vmwait (6 / 5 / 0 tail).
// ---------------------------------------------------------------------------
__global__ __launch_bounds__(256, 3) void head_kernel(
    const short* __restrict__ xb, const float2* __restrict__ murs,
    const short* __restrict__ hwbT, const float* __restrict__ hbias,
    const float* __restrict__ csumv,
    const u64* __restrict__ counts, const int* __restrict__ rowlist,
    float* __restrict__ out)
{
    const int e = blockIdx.z;
    int cnt = (int)((*counts >> (16 * e)) & 0xFFFFull);
    if (cnt > NB) cnt = NB;
    const int rc0 = blockIdx.y * 64;
    if (rc0 >= cnt) return;
    const int n0 = blockIdx.x * 256;

    __shared__ __align__(16) short As[4][2048];      // ring-4: 64 rows x 32k
    __shared__ __align__(16) short Bs[2][8192];      // dbuf: 256c x 32k
    __shared__ float hbs[256], css[256], rs_s[64], rm_s[64];
    __shared__ int rows_s[64];

    const int t = threadIdx.x;
    const int w = t >> 6, l = t & 63;
    const int g = l >> 4, lm = l & 15;
    const int sr = t >> 2, sq = t & 3;

    if (t < 64) {
        const int ri = rc0 + t;
        int rr = (ri < cnt) ? rowlist[e * NB + ri] : -1;
        if (rr >= NB) rr = -1;
        rows_s[t] = rr;
        const float2 mr = (rr >= 0) ? murs[rr] : make_float2(0.f, 0.f);
        rs_s[t] = mr.y;
        rm_s[t] = mr.y * mr.x;   // rs*mu
    }
    hbs[t] = (n0 + t < NC) ? hbias[e * NCP + n0 + t] : 0.f;
    css[t] = (n0 + t < NC) ? csumv[e * NCP + n0 + t] : 0.f;

    const int ridx = rc0 + sr;
    int arow = (ridx < cnt) ? rowlist[e * NB + ridx] : 0;
    if ((unsigned)arow >= NB) arow = 0;
    const int aslot = sq ^ ((sr >> 1) & 3);
    const short* axsrc = xb + (size_t)arow * ND + aslot * 8;
    const short* hwe = hwbT + (size_t)e * NCP * ND + (size_t)n0 * ND;
    const int aoff = __builtin_amdgcn_readfirstlane(w * 512);

    v4f acc[4][4];
    #pragma unroll
    for (int i = 0; i < 4; ++i)
        #pragma unroll
        for (int j = 0; j < 4; ++j) acc[i][j] = (v4f)(0.f);

    // prologue: B(0)x4, then A(0), A(1). (__syncthreads drains them once.)
    #pragma unroll
    for (int i = 0; i < 4; ++i) {
        const int crow = w * 64 + i * 16 + (l >> 2);
        const int off = __builtin_amdgcn_readfirstlane((w * 64 + i * 16) * 32);
        GLD16(hwe + (size_t)crow * ND + (l & 3) * 8, &Bs[0][0] + off);
    }
    GLD16(axsrc,      &As[0][0] + aoff);
    GLD16(axsrc + 32, &As[1][0] + aoff);
    __syncthreads();   // rows_s/hbs visible; prologue loads landed

    #pragma unroll
    for (int ks = 0; ks < 24; ++ks) {
        const int curA = ks & 3;
        const int curB = ks & 1;
        if (ks < 23) {
            #pragma unroll
            for (int i = 0; i < 4; ++i) {
                const int crow = w * 64 + i * 16 + (l >> 2);
                const int off = __builtin_amdgcn_readfirstlane((w * 64 + i * 16) * 32);
                GLD16(hwe + (size_t)crow * ND + (ks + 1) * 32 + (l & 3) * 8,
                      &Bs[(ks + 1) & 1][0] + off);
            }
        }
        if (ks < 22) {
            GLD16(axsrc + (ks + 2) * 32, &As[(ks + 2) & 3][0] + aoff);
        }
        if (ks < 22)       vmwait(6);
        else if (ks == 22) vmwait(5);
        else               vmwait(0);
        __builtin_amdgcn_sched_barrier(0);
        __builtin_amdgcn_s_barrier();          // stage ks landed everywhere

        v8s af[4];
        #pragma unroll
        for (int mf = 0; mf < 4; ++mf) {
            const int row = mf * 16 + lm;
            af[mf] = *(const v8s*)&As[curA][row * 32 + (g ^ ((lm >> 1) & 3)) * 8];
        }
        #pragma unroll
        for (int nf = 0; nf < 4; ++nf) {
            const int cl = w * 64 + nf * 16 + lm;
            const v8s bv = *(const v8s*)&Bs[curB][cl * 32 + (g ^ ((lm >> 1) & 3)) * 8];
            #pragma unroll
            for (int mf = 0; mf < 4; ++mf)
                acc[mf][nf] = __builtin_amdgcn_mfma_f32_16x16x32_bf16(
                    af[mf], bv, acc[mf][nf], 0, 0, 0);
        }
        asm volatile("s_waitcnt lgkmcnt(0)" ::: "memory");
        __builtin_amdgcn_sched_barrier(0);
    }

    #pragma unroll
    for (int mf = 0; mf < 4; ++mf) {
        #pragma unroll
        for (int r = 0; r < 4; ++r) {
            const int rl = mf * 16 + g * 4 + r;
            const int orow = rows_s[rl];
            if (orow < 0) continue;
            const float rs = rs_s[rl], rm = rm_s[rl];
            float* op = out + (size_t)orow * NC;
            #pragma unroll
            for (int nf = 0; nf < 4; ++nf) {
                const int cl = w * 64 + nf * 16 + lm;
                const int c = n0 + cl;
                if (c < NC)
                    op[c] = acc[mf][nf][r] * rs - rm * css[cl] + hbs[cl];
            }
        }
    }
}

extern "C" void kernel_launch(void* const* d_in, const int* in_sizes, int n_in,
                              void* d_out, int out_size, void* d_ws, size_t ws_size,
                              hipStream_t stream) {
    const float* x     = (const float*)d_in[0];
    const float* gum   = (const float*)d_in[1];
    const float* w1    = (const float*)d_in[2];
    const float* b1    = (const float*)d_in[3];
    const float* w2    = (const float*)d_in[4];
    const float* b2    = (const float*)d_in[5];
    const float* gamma = (const float*)d_in[6];
    const float* beta  = (const float*)d_in[7];
    const float* hw    = (const float*)d_in[8];
    const float* hb    = (const float*)d_in[9];
    float* out = (float*)d_out;

    char* ws = (char*)d_ws;
    u64*    counts   = (u64*)ws;                    // packed 4x16-bit counters
    float2* murs     = (float2*)(ws + 256);         // 262144 B
    int*    rowlist  = (int*)(ws + 262400);         // 393216 B
    int*    redolist = (int*)(ws + 655616);         // 131072 B
    float*  hbias    = (float*)(ws + 786688);       // 6144 B (atomic-accumulated)
    float*  csumv    = (float*)(ws + 792832);       // 6144 B (atomic-accumulated)
    short*  w1bT     = (short*)(ws + 798976);       // 196608 B
    short*  hwbT     = (short*)(ws + 995584);       // 2359296 B -> 3354880
    short*  xbg      = (short*)(ws + XB_OFF);       // 50 MB

    hipMemsetAsync(hbias, 0, 12288, stream);        // hbias + csumv (adjacent)
    prep_kernel<<<624, 256, 0, stream>>>(hw, gamma, beta, w1, hb,
                                         hwbT, w1bT, hbias, csumv, counts);
    lnsel_kernel<<<NB / 64, 256, 0, stream>>>(x, gum, w1bT, b1, w2, b2,
                                              murs, xbg, counts,
                                              rowlist, redolist);
    redo_kernel<<<1024, 128, 0, stream>>>(x, gum, w1, b1, w2, b2,
                                          counts, rowlist, redolist);
    head_kernel<<<dim3(2, NB / 64, NE), 256, 0, stream>>>(
        xbg, murs, hwbT, hbias, csumv, counts, rowlist, out);
}